// Round 2
// baseline (747.595 us; speedup 1.0000x reference)
//
#include <hip/hip_runtime.h>
#include <stdint.h>

// Problem constants
#define B_  4
#define S_  2048
#define D_  1024
#define H_  16
#define DK_ 64
#define M_  8192   // B_*S_

typedef __attribute__((ext_vector_type(8))) short bf16x8;
typedef __attribute__((ext_vector_type(4))) float f32x4;

static __device__ __forceinline__ short f2bf(float f) {
  union { float f; uint32_t u; } c; c.f = f;
  uint32_t u = c.u;
  uint32_t r = (u + 0x7FFFu + ((u >> 16) & 1u)) >> 16;  // RNE
  return (short)r;
}
static __device__ __forceinline__ float bf2f(short h) {
  union { uint32_t u; float f; } c; c.u = ((uint32_t)(uint16_t)h) << 16;
  return c.f;
}
static __device__ __forceinline__ void split1(float v, short& hi, short& lo) {
  hi = f2bf(v);
  lo = f2bf(v - bf2f(hi));
}

// ---------------------------------------------------------------------------
// Weight convert+transpose+split: for each of 4 weights, Wt_hi[n][k] and
// Wt_lo[n][k] bf16 with hi+lo ~= fp32 W[k][n]. Block order: 2z=hi, 2z+1=lo.
// ---------------------------------------------------------------------------
__global__ __launch_bounds__(256) void kw_split(
    const float* __restrict__ w0, const float* __restrict__ w1,
    const float* __restrict__ w2, const float* __restrict__ w3,
    short* __restrict__ wt)
{
  __shared__ float tile[32][33];
  const float* src;
  switch (blockIdx.z) { case 0: src = w0; break; case 1: src = w1; break;
                        case 2: src = w2; break; default: src = w3; }
  short* dhi = wt + (size_t)(2 * blockIdx.z) * (1024u * 1024u);
  short* dlo = dhi + (size_t)(1024u * 1024u);
  const int x = threadIdx.x, y = threadIdx.y;            // (32, 8)
  const int c0 = blockIdx.x * 32, r0 = blockIdx.y * 32;
#pragma unroll
  for (int i = 0; i < 4; i++)
    tile[y + 8 * i][x] = src[(size_t)(r0 + y + 8 * i) * 1024 + c0 + x];
  __syncthreads();
#pragma unroll
  for (int i = 0; i < 4; i++) {
    float v = tile[x][y + 8 * i];
    short sh, sl; split1(v, sh, sl);
    const size_t off = (size_t)(c0 + y + 8 * i) * 1024 + r0 + x;
    dhi[off] = sh; dlo[off] = sl;
  }
}

// ---------------------------------------------------------------------------
// Split-precision projection for Q (z=0, scaled 0.125) and K (z=1):
// C = A(fp32) @ W(fp32), computed as (Ahi+Alo)(Whi+Wlo) dropping lo*lo.
// Output: head-split [B,H,S,dk] as bf16 hi/lo pair tensors.
// 128x128 tile, 4 waves (2x2 of 64x64), BK=32.
// ---------------------------------------------------------------------------
__global__ __launch_bounds__(256) void kproj_qk(
    const float* __restrict__ a0, const float* __restrict__ a1,
    const short* __restrict__ wt, short* __restrict__ outbase)
{
  __shared__ short Ahi[128][40];
  __shared__ short Alo[128][40];
  __shared__ short Whi[128][40];
  __shared__ short Wlo[128][40];

  const int m0 = blockIdx.x * 128;
  const int n0 = blockIdx.y * 128;
  const int z  = blockIdx.z;                 // 0=Q, 1=K

  const float* af  = z ? a1 : a0;
  const short* whi = wt + (size_t)(2 * z) * (1024u * 1024u);
  const short* wlo = whi + (size_t)(1024u * 1024u);
  short* ohi = outbase + (size_t)z * (2u * (size_t)M_ * 1024u);
  short* olo = ohi + (size_t)M_ * 1024u;
  const float scale = (z == 0) ? 0.125f : 1.0f;

  const int tid  = threadIdx.x;
  const int w    = tid >> 6, lane = tid & 63;
  const int g    = lane >> 4, x = lane & 15;
  const int wr   = w >> 1, wc = w & 1;
  const int srow = tid >> 1, shalf = tid & 1;

  f32x4 acc[4][4];
#pragma unroll
  for (int mi = 0; mi < 4; mi++)
#pragma unroll
    for (int ni = 0; ni < 4; ni++) acc[mi][ni] = f32x4{0.f, 0.f, 0.f, 0.f};

  for (int k0 = 0; k0 < 1024; k0 += 32) {
    // ---- stage A tile (128x32 fp32 -> hi/lo) ----
    {
      const float* ap = af + (size_t)(m0 + srow) * 1024 + k0 + shalf * 16;
      f32x4 f4[4];
      f4[0] = *(const f32x4*)(ap + 0);
      f4[1] = *(const f32x4*)(ap + 4);
      f4[2] = *(const f32x4*)(ap + 8);
      f4[3] = *(const f32x4*)(ap + 12);
      bf16x8 h0, h1, l0, l1;
#pragma unroll
      for (int j = 0; j < 4; j++) {
        short sh, sl;
        split1(f4[0][j], sh, sl); h0[j] = sh;     l0[j] = sl;
        split1(f4[1][j], sh, sl); h0[4 + j] = sh; l0[4 + j] = sl;
        split1(f4[2][j], sh, sl); h1[j] = sh;     l1[j] = sl;
        split1(f4[3][j], sh, sl); h1[4 + j] = sh; l1[4 + j] = sl;
      }
      *(bf16x8*)&Ahi[srow][shalf * 16 + 0] = h0;
      *(bf16x8*)&Ahi[srow][shalf * 16 + 8] = h1;
      *(bf16x8*)&Alo[srow][shalf * 16 + 0] = l0;
      *(bf16x8*)&Alo[srow][shalf * 16 + 8] = l1;
    }
    // ---- stage W hi/lo tiles (128n x 32k) ----
    {
      const short* ph = whi + (size_t)(n0 + srow) * 1024 + k0 + shalf * 16;
      const short* pl = wlo + (size_t)(n0 + srow) * 1024 + k0 + shalf * 16;
      *(bf16x8*)&Whi[srow][shalf * 16 + 0] = *(const bf16x8*)(ph + 0);
      *(bf16x8*)&Whi[srow][shalf * 16 + 8] = *(const bf16x8*)(ph + 8);
      *(bf16x8*)&Wlo[srow][shalf * 16 + 0] = *(const bf16x8*)(pl + 0);
      *(bf16x8*)&Wlo[srow][shalf * 16 + 8] = *(const bf16x8*)(pl + 8);
    }
    __syncthreads();

    bf16x8 ah[4], al[4], bh[4], bl[4];
#pragma unroll
    for (int mi = 0; mi < 4; mi++) {
      ah[mi] = *(const bf16x8*)&Ahi[wr * 64 + mi * 16 + x][8 * g];
      al[mi] = *(const bf16x8*)&Alo[wr * 64 + mi * 16 + x][8 * g];
    }
#pragma unroll
    for (int ni = 0; ni < 4; ni++) {
      bh[ni] = *(const bf16x8*)&Whi[wc * 64 + ni * 16 + x][8 * g];
      bl[ni] = *(const bf16x8*)&Wlo[wc * 64 + ni * 16 + x][8 * g];
    }
#pragma unroll
    for (int mi = 0; mi < 4; mi++)
#pragma unroll
      for (int ni = 0; ni < 4; ni++) {
        acc[mi][ni] = __builtin_amdgcn_mfma_f32_16x16x32_bf16(
            ah[mi], bh[ni], acc[mi][ni], 0, 0, 0);
        acc[mi][ni] = __builtin_amdgcn_mfma_f32_16x16x32_bf16(
            ah[mi], bl[ni], acc[mi][ni], 0, 0, 0);
        acc[mi][ni] = __builtin_amdgcn_mfma_f32_16x16x32_bf16(
            al[mi], bh[ni], acc[mi][ni], 0, 0, 0);
      }
    __syncthreads();
  }

  // ---- epilogue: scale, split, write [B,H,S,dk] hi/lo ----
#pragma unroll
  for (int mi = 0; mi < 4; mi++) {
    const int mrow = m0 + wr * 64 + mi * 16 + g * 4;
#pragma unroll
    for (int ni = 0; ni < 4; ni++) {
      const int ncol = n0 + wc * 64 + ni * 16 + x;
#pragma unroll
      for (int r = 0; r < 4; r++) {
        const float v = acc[mi][ni][r] * scale;
        const int row = mrow + r;
        const int b = row >> 11, s = row & 2047;
        const int hh = ncol >> 6, dd = ncol & 63;
        const size_t off = (((size_t)b * H_ + hh) * S_ + s) * DK_ + dd;
        short sh, sl; split1(v, sh, sl);
        ohi[off] = sh; olo[off] = sl;
      }
    }
  }
}

// ---------------------------------------------------------------------------
// Plain bf16 GEMM. MODE 0: A fp32 (V projection) -> bf16 head layout.
//                  MODE 1: A bf16 flat (out proj) -> fp32 flat.
// ---------------------------------------------------------------------------
template<int MODE>
__global__ __launch_bounds__(256) void kgemm(
    const float* __restrict__ af, const short* __restrict__ ab,
    const short* __restrict__ wtp, short* __restrict__ outb,
    float* __restrict__ outf)
{
  __shared__ short Alds[128][40];
  __shared__ short Wlds[128][40];

  const int m0 = blockIdx.x * 128;
  const int n0 = blockIdx.y * 128;

  const int tid  = threadIdx.x;
  const int w    = tid >> 6, lane = tid & 63;
  const int g    = lane >> 4, x = lane & 15;
  const int wr   = w >> 1, wc = w & 1;
  const int srow = tid >> 1, shalf = tid & 1;

  f32x4 acc[4][4];
#pragma unroll
  for (int mi = 0; mi < 4; mi++)
#pragma unroll
    for (int ni = 0; ni < 4; ni++) acc[mi][ni] = f32x4{0.f, 0.f, 0.f, 0.f};

  for (int k0 = 0; k0 < 1024; k0 += 32) {
    if constexpr (MODE == 0) {
      const float* ap = af + (size_t)(m0 + srow) * 1024 + k0 + shalf * 16;
      f32x4 fa = *(const f32x4*)(ap + 0);
      f32x4 fb = *(const f32x4*)(ap + 4);
      f32x4 fc = *(const f32x4*)(ap + 8);
      f32x4 fd = *(const f32x4*)(ap + 12);
      bf16x8 h0, h1;
#pragma unroll
      for (int j = 0; j < 4; j++) {
        h0[j] = f2bf(fa[j]); h0[4 + j] = f2bf(fb[j]);
        h1[j] = f2bf(fc[j]); h1[4 + j] = f2bf(fd[j]);
      }
      *(bf16x8*)&Alds[srow][shalf * 16 + 0] = h0;
      *(bf16x8*)&Alds[srow][shalf * 16 + 8] = h1;
    } else {
      const short* ap = ab + (size_t)(m0 + srow) * 1024 + k0 + shalf * 16;
      *(bf16x8*)&Alds[srow][shalf * 16 + 0] = *(const bf16x8*)(ap + 0);
      *(bf16x8*)&Alds[srow][shalf * 16 + 8] = *(const bf16x8*)(ap + 8);
    }
    {
      const short* wp = wtp + (size_t)(n0 + srow) * 1024 + k0 + shalf * 16;
      *(bf16x8*)&Wlds[srow][shalf * 16 + 0] = *(const bf16x8*)(wp + 0);
      *(bf16x8*)&Wlds[srow][shalf * 16 + 8] = *(const bf16x8*)(wp + 8);
    }
    __syncthreads();

    bf16x8 afr[4], bfr[4];
#pragma unroll
    for (int mi = 0; mi < 4; mi++)
      afr[mi] = *(const bf16x8*)&Alds[wr * 64 + mi * 16 + x][8 * g];
#pragma unroll
    for (int ni = 0; ni < 4; ni++)
      bfr[ni] = *(const bf16x8*)&Wlds[wc * 64 + ni * 16 + x][8 * g];
#pragma unroll
    for (int mi = 0; mi < 4; mi++)
#pragma unroll
      for (int ni = 0; ni < 4; ni++)
        acc[mi][ni] = __builtin_amdgcn_mfma_f32_16x16x32_bf16(
            afr[mi], bfr[ni], acc[mi][ni], 0, 0, 0);
    __syncthreads();
  }

#pragma unroll
  for (int mi = 0; mi < 4; mi++) {
    const int mrow = m0 + wr * 64 + mi * 16 + g * 4;
#pragma unroll
    for (int ni = 0; ni < 4; ni++) {
      const int ncol = n0 + wc * 64 + ni * 16 + x;
#pragma unroll
      for (int r = 0; r < 4; r++) {
        const float v = acc[mi][ni][r];
        const int row = mrow + r;
        if constexpr (MODE == 0) {
          const int b = row >> 11, s = row & 2047;
          const int hh = ncol >> 6, dd = ncol & 63;
          outb[(((size_t)b * H_ + hh) * S_ + s) * DK_ + dd] = f2bf(v);
        } else {
          outf[(size_t)row * 1024 + ncol] = v;
        }
      }
    }
  }
}

// ---------------------------------------------------------------------------
// Causal flash attention; Q,K as bf16 hi/lo pairs (3-MFMA split QK^T), V bf16.
// Grid (32 qblocks, 64 b*h). 4 waves x 16 q rows, KV tile 32.
// Softmax scale pre-folded into Q at projection time.
// ---------------------------------------------------------------------------
__global__ __launch_bounds__(256) void kattn(
    const short* __restrict__ Qhi, const short* __restrict__ Qlo,
    const short* __restrict__ Khi, const short* __restrict__ Klo,
    const short* __restrict__ Vh,  short* __restrict__ AO)
{
  __shared__ short KldsH[32][72];
  __shared__ short KldsL[32][72];
  __shared__ short Vtlds[64][40];
  __shared__ short Plds[4][16][40];

  const int qblk = blockIdx.x;          // 0..31
  const int bh   = blockIdx.y;          // 0..63
  const int qb   = qblk * 64;
  const int tid  = threadIdx.x;
  const int w    = tid >> 6, lane = tid & 63;
  const int g    = lane >> 4, x = lane & 15;

  const size_t bhoff = (size_t)bh * S_ * DK_;
  const short* KgH = Khi + bhoff;
  const short* KgL = Klo + bhoff;
  const short* Vg  = Vh + bhoff;

  const int qrow = qb + w * 16 + x;
  bf16x8 qh[2], ql[2];
#pragma unroll
  for (int ds = 0; ds < 2; ds++) {
    qh[ds] = *(const bf16x8*)(Qhi + bhoff + (size_t)qrow * DK_ + ds * 32 + 8 * g);
    ql[ds] = *(const bf16x8*)(Qlo + bhoff + (size_t)qrow * DK_ + ds * 32 + 8 * g);
  }

  f32x4 ow[4];
#pragma unroll
  for (int dt = 0; dt < 4; dt++) ow[dt] = f32x4{0.f, 0.f, 0.f, 0.f};
  float mrow[4], lsum[4];
#pragma unroll
  for (int r = 0; r < 4; r++) { mrow[r] = -1e30f; lsum[r] = 0.f; }

  const int srow8 = tid >> 3, sc = tid & 7;   // staging coords

  const int kvend = qb + 32;                   // last kv tile base
  for (int kvb = 0; kvb <= kvend; kvb += 32) {
    __syncthreads();  // previous iteration's K/V reads must complete
    {
      bf16x8 kk = *(const bf16x8*)(KgH + (size_t)(kvb + srow8) * DK_ + sc * 8);
      *(bf16x8*)&KldsH[srow8][sc * 8] = kk;
      bf16x8 kl = *(const bf16x8*)(KgL + (size_t)(kvb + srow8) * DK_ + sc * 8);
      *(bf16x8*)&KldsL[srow8][sc * 8] = kl;
      bf16x8 vv = *(const bf16x8*)(Vg + (size_t)(kvb + srow8) * DK_ + sc * 8);
      short va[8];
      *(bf16x8*)va = vv;
#pragma unroll
      for (int i = 0; i < 8; i++) {            // rotated write order
        const int e = (sc + i) & 7;
        Vtlds[sc * 8 + e][srow8] = va[e];
      }
    }
    __syncthreads();

    // ---- split QK^T : S[q 16][kv 32] per wave ----
    f32x4 sacc[2];
    sacc[0] = f32x4{0.f, 0.f, 0.f, 0.f};
    sacc[1] = f32x4{0.f, 0.f, 0.f, 0.f};
#pragma unroll
    for (int nt = 0; nt < 2; nt++)
#pragma unroll
      for (int ds = 0; ds < 2; ds++) {
        bf16x8 kfh = *(const bf16x8*)&KldsH[nt * 16 + x][ds * 32 + 8 * g];
        bf16x8 kfl = *(const bf16x8*)&KldsL[nt * 16 + x][ds * 32 + 8 * g];
        sacc[nt] = __builtin_amdgcn_mfma_f32_16x16x32_bf16(
            qh[ds], kfh, sacc[nt], 0, 0, 0);
        sacc[nt] = __builtin_amdgcn_mfma_f32_16x16x32_bf16(
            qh[ds], kfl, sacc[nt], 0, 0, 0);
        sacc[nt] = __builtin_amdgcn_mfma_f32_16x16x32_bf16(
            ql[ds], kfh, sacc[nt], 0, 0, 0);
      }

    // ---- causal mask ----
    if (kvb + 31 > qb + w * 16) {
#pragma unroll
      for (int nt = 0; nt < 2; nt++) {
        const int kvg = kvb + nt * 16 + x;
#pragma unroll
        for (int r = 0; r < 4; r++) {
          const int qg = qb + w * 16 + g * 4 + r;
          if (kvg > qg) sacc[nt][r] = -1e30f;
        }
      }
    }

    // ---- online softmax ----
    float mnew[4], alpha[4];
#pragma unroll
    for (int r = 0; r < 4; r++) {
      float t = fmaxf(sacc[0][r], sacc[1][r]);
      t = fmaxf(t, __shfl_xor(t, 1));
      t = fmaxf(t, __shfl_xor(t, 2));
      t = fmaxf(t, __shfl_xor(t, 4));
      t = fmaxf(t, __shfl_xor(t, 8));
      mnew[r]  = fmaxf(mrow[r], t);
      alpha[r] = __expf(mrow[r] - mnew[r]);
      mrow[r]  = mnew[r];
    }
#pragma unroll
    for (int r = 0; r < 4; r++) {
      const float p0 = __expf(sacc[0][r] - mnew[r]);
      const float p1 = __expf(sacc[1][r] - mnew[r]);
      sacc[0][r] = p0; sacc[1][r] = p1;
      float rs = p0 + p1;
      rs += __shfl_xor(rs, 1);
      rs += __shfl_xor(rs, 2);
      rs += __shfl_xor(rs, 4);
      rs += __shfl_xor(rs, 8);
      lsum[r] = lsum[r] * alpha[r] + rs;
    }
#pragma unroll
    for (int nt = 0; nt < 2; nt++)
#pragma unroll
      for (int r = 0; r < 4; r++)
        Plds[w][g * 4 + r][nt * 16 + x] = f2bf(sacc[nt][r]);
#pragma unroll
    for (int dt = 0; dt < 4; dt++)
#pragma unroll
      for (int r = 0; r < 4; r++) ow[dt][r] *= alpha[r];

    asm volatile("s_waitcnt lgkmcnt(0)" ::: "memory");
    __builtin_amdgcn_sched_barrier(0);

    // ---- PV : O[q 16][d 64] ----
    bf16x8 pf = *(const bf16x8*)&Plds[w][x][8 * g];
#pragma unroll
    for (int dt = 0; dt < 4; dt++) {
      bf16x8 vf = *(const bf16x8*)&Vtlds[dt * 16 + x][8 * g];
      ow[dt] = __builtin_amdgcn_mfma_f32_16x16x32_bf16(pf, vf, ow[dt], 0, 0, 0);
    }
  }

  // ---- epilogue: normalize, write merged-head AO [B,S,D] bf16 ----
  const int b = bh >> 4, h = bh & 15;
#pragma unroll
  for (int r = 0; r < 4; r++) {
    const float inv = 1.0f / lsum[r];
    const int row = qb + w * 16 + g * 4 + r;
    const size_t base = ((size_t)b * S_ + row) * D_ + h * DK_;
#pragma unroll
    for (int dt = 0; dt < 4; dt++)
      AO[base + dt * 16 + x] = f2bf(ow[dt][r] * inv);
  }
}

// ---------------------------------------------------------------------------
extern "C" void kernel_launch(void* const* d_in, const int* in_sizes, int n_in,
                              void* d_out, int out_size, void* d_ws, size_t ws_size,
                              hipStream_t stream) {
  (void)in_sizes; (void)n_in; (void)out_size; (void)ws_size;
  const float* q  = (const float*)d_in[0];
  const float* k  = (const float*)d_in[1];
  const float* v  = (const float*)d_in[2];
  const float* wq = (const float*)d_in[3];
  const float* wk = (const float*)d_in[4];
  const float* wv = (const float*)d_in[5];
  const float* wo = (const float*)d_in[6];
  float* out = (float*)d_out;

  // Workspace layout (MB):
  //   0..16   WT: 8 x [1024][1024] bf16 (wq_hi,wq_lo,wk_hi,wk_lo,wv_hi,wv_lo,wo_hi,wo_lo)
  //   16..32  QHhi   32..48 QHlo   48..64 KHhi   64..80 KHlo   (head-split bf16)
  //   80..96  VH (head-split bf16)
  //   96..112 AO ([B,S,D] bf16)
  char* ws = (char*)d_ws;
  short* WT   = (short*)ws;
  short* QKH  = (short*)(ws + (size_t)16 * 1024 * 1024);  // Q/K hi/lo base
  short* QHhi = QKH;
  short* QHlo = (short*)(ws + (size_t)32 * 1024 * 1024);
  short* KHhi = (short*)(ws + (size_t)48 * 1024 * 1024);
  short* KHlo = (short*)(ws + (size_t)64 * 1024 * 1024);
  short* VH   = (short*)(ws + (size_t)80 * 1024 * 1024);
  short* AO   = (short*)(ws + (size_t)96 * 1024 * 1024);

  const short* WVhi = WT + (size_t)4 * 1024 * 1024;
  const short* WOhi = WT + (size_t)6 * 1024 * 1024;

  kw_split<<<dim3(32, 32, 4), dim3(32, 8, 1), 0, stream>>>(wq, wk, wv, wo, WT);
  kproj_qk<<<dim3(64, 8, 2), dim3(256), 0, stream>>>(q, k, WT, QKH);
  kgemm<0><<<dim3(64, 8), dim3(256), 0, stream>>>(v, nullptr, WVhi, VH, nullptr);
  kattn<<<dim3(32, 64), dim3(256), 0, stream>>>(QHhi, QHlo, KHhi, KHlo, VH, AO);
  kgemm<1><<<dim3(64, 8), dim3(256), 0, stream>>>(nullptr, AO, WOhi, nullptr, out);
}

// Round 3
// 552.144 us; speedup vs baseline: 1.3540x; 1.3540x over previous
//
#include <hip/hip_runtime.h>
#include <stdint.h>

// Problem constants
#define B_  4
#define S_  2048
#define D_  1024
#define H_  16
#define DK_ 64
#define M_  8192   // B_*S_

typedef __attribute__((ext_vector_type(8))) short bf16x8;
typedef __attribute__((ext_vector_type(4))) float f32x4;

static __device__ __forceinline__ short f2bf(float f) {
  union { float f; uint32_t u; } c; c.f = f;
  uint32_t u = c.u;
  uint32_t r = (u + 0x7FFFu + ((u >> 16) & 1u)) >> 16;  // RNE
  return (short)r;
}
static __device__ __forceinline__ float bf2f(short h) {
  union { uint32_t u; float f; } c; c.u = ((uint32_t)(uint16_t)h) << 16;
  return c.f;
}
static __device__ __forceinline__ void split1(float v, short& hi, short& lo) {
  hi = f2bf(v);
  lo = f2bf(v - bf2f(hi));
}

// ---------------------------------------------------------------------------
// Weight convert+transpose+split: for each of 4 weights, Wt_hi[n][k] and
// Wt_lo[n][k] bf16 with hi+lo ~= fp32 W[k][n]. Block order: 2z=hi, 2z+1=lo.
// ---------------------------------------------------------------------------
__global__ __launch_bounds__(256) void kw_split(
    const float* __restrict__ w0, const float* __restrict__ w1,
    const float* __restrict__ w2, const float* __restrict__ w3,
    short* __restrict__ wt)
{
  __shared__ float tile[32][33];
  const float* src;
  switch (blockIdx.z) { case 0: src = w0; break; case 1: src = w1; break;
                        case 2: src = w2; break; default: src = w3; }
  short* dhi = wt + (size_t)(2 * blockIdx.z) * (1024u * 1024u);
  short* dlo = dhi + (size_t)(1024u * 1024u);
  const int x = threadIdx.x, y = threadIdx.y;            // (32, 8)
  const int c0 = blockIdx.x * 32, r0 = blockIdx.y * 32;
#pragma unroll
  for (int i = 0; i < 4; i++)
    tile[y + 8 * i][x] = src[(size_t)(r0 + y + 8 * i) * 1024 + c0 + x];
  __syncthreads();
#pragma unroll
  for (int i = 0; i < 4; i++) {
    float v = tile[x][y + 8 * i];
    short sh, sl; split1(v, sh, sl);
    const size_t off = (size_t)(c0 + y + 8 * i) * 1024 + r0 + x;
    dhi[off] = sh; dlo[off] = sl;
  }
}

// ---------------------------------------------------------------------------
// Split-precision projection for Q (z=0, scaled 0.125*log2e) and K (z=1):
// C = A(fp32) @ W(fp32), computed as (Ahi+Alo)(Whi+Wlo) dropping lo*lo.
// Output: head-split [B,H,S,dk] as bf16 hi/lo pair tensors.
// ---------------------------------------------------------------------------
__global__ __launch_bounds__(256) void kproj_qk(
    const float* __restrict__ a0, const float* __restrict__ a1,
    const short* __restrict__ wt, short* __restrict__ outbase)
{
  __shared__ short Ahi[128][40];
  __shared__ short Alo[128][40];
  __shared__ short Whi[128][40];
  __shared__ short Wlo[128][40];

  const int m0 = blockIdx.x * 128;
  const int n0 = blockIdx.y * 128;
  const int z  = blockIdx.z;                 // 0=Q, 1=K

  const float* af  = z ? a1 : a0;
  const short* whi = wt + (size_t)(2 * z) * (1024u * 1024u);
  const short* wlo = whi + (size_t)(1024u * 1024u);
  short* ohi = outbase + (size_t)z * (2u * (size_t)M_ * 1024u);
  short* olo = ohi + (size_t)M_ * 1024u;
  // Q carries softmax scale AND log2(e) fold so attention uses exp2 directly.
  const float scale = (z == 0) ? 0.18033688011112042f : 1.0f;  // 0.125*log2e

  const int tid  = threadIdx.x;
  const int w    = tid >> 6, lane = tid & 63;
  const int g    = lane >> 4, x = lane & 15;
  const int wr   = w >> 1, wc = w & 1;
  const int srow = tid >> 1, shalf = tid & 1;

  f32x4 acc[4][4];
#pragma unroll
  for (int mi = 0; mi < 4; mi++)
#pragma unroll
    for (int ni = 0; ni < 4; ni++) acc[mi][ni] = f32x4{0.f, 0.f, 0.f, 0.f};

  for (int k0 = 0; k0 < 1024; k0 += 32) {
    // ---- stage A tile (128x32 fp32 -> hi/lo) ----
    {
      const float* ap = af + (size_t)(m0 + srow) * 1024 + k0 + shalf * 16;
      f32x4 f4[4];
      f4[0] = *(const f32x4*)(ap + 0);
      f4[1] = *(const f32x4*)(ap + 4);
      f4[2] = *(const f32x4*)(ap + 8);
      f4[3] = *(const f32x4*)(ap + 12);
      bf16x8 h0, h1, l0, l1;
#pragma unroll
      for (int j = 0; j < 4; j++) {
        short sh, sl;
        split1(f4[0][j], sh, sl); h0[j] = sh;     l0[j] = sl;
        split1(f4[1][j], sh, sl); h0[4 + j] = sh; l0[4 + j] = sl;
        split1(f4[2][j], sh, sl); h1[j] = sh;     l1[j] = sl;
        split1(f4[3][j], sh, sl); h1[4 + j] = sh; l1[4 + j] = sl;
      }
      *(bf16x8*)&Ahi[srow][shalf * 16 + 0] = h0;
      *(bf16x8*)&Ahi[srow][shalf * 16 + 8] = h1;
      *(bf16x8*)&Alo[srow][shalf * 16 + 0] = l0;
      *(bf16x8*)&Alo[srow][shalf * 16 + 8] = l1;
    }
    // ---- stage W hi/lo tiles (128n x 32k) ----
    {
      const short* ph = whi + (size_t)(n0 + srow) * 1024 + k0 + shalf * 16;
      const short* pl = wlo + (size_t)(n0 + srow) * 1024 + k0 + shalf * 16;
      *(bf16x8*)&Whi[srow][shalf * 16 + 0] = *(const bf16x8*)(ph + 0);
      *(bf16x8*)&Whi[srow][shalf * 16 + 8] = *(const bf16x8*)(ph + 8);
      *(bf16x8*)&Wlo[srow][shalf * 16 + 0] = *(const bf16x8*)(pl + 0);
      *(bf16x8*)&Wlo[srow][shalf * 16 + 8] = *(const bf16x8*)(pl + 8);
    }
    __syncthreads();

    bf16x8 ah[4], al[4], bh[4], bl[4];
#pragma unroll
    for (int mi = 0; mi < 4; mi++) {
      ah[mi] = *(const bf16x8*)&Ahi[wr * 64 + mi * 16 + x][8 * g];
      al[mi] = *(const bf16x8*)&Alo[wr * 64 + mi * 16 + x][8 * g];
    }
#pragma unroll
    for (int ni = 0; ni < 4; ni++) {
      bh[ni] = *(const bf16x8*)&Whi[wc * 64 + ni * 16 + x][8 * g];
      bl[ni] = *(const bf16x8*)&Wlo[wc * 64 + ni * 16 + x][8 * g];
    }
#pragma unroll
    for (int mi = 0; mi < 4; mi++)
#pragma unroll
      for (int ni = 0; ni < 4; ni++) {
        acc[mi][ni] = __builtin_amdgcn_mfma_f32_16x16x32_bf16(
            ah[mi], bh[ni], acc[mi][ni], 0, 0, 0);
        acc[mi][ni] = __builtin_amdgcn_mfma_f32_16x16x32_bf16(
            ah[mi], bl[ni], acc[mi][ni], 0, 0, 0);
        acc[mi][ni] = __builtin_amdgcn_mfma_f32_16x16x32_bf16(
            al[mi], bh[ni], acc[mi][ni], 0, 0, 0);
      }
    __syncthreads();
  }

  // ---- epilogue: scale, split, write [B,H,S,dk] hi/lo ----
#pragma unroll
  for (int mi = 0; mi < 4; mi++) {
    const int mrow = m0 + wr * 64 + mi * 16 + g * 4;
#pragma unroll
    for (int ni = 0; ni < 4; ni++) {
      const int ncol = n0 + wc * 64 + ni * 16 + x;
#pragma unroll
      for (int r = 0; r < 4; r++) {
        const float v = acc[mi][ni][r] * scale;
        const int row = mrow + r;
        const int b = row >> 11, s = row & 2047;
        const int hh = ncol >> 6, dd = ncol & 63;
        const size_t off = (((size_t)b * H_ + hh) * S_ + s) * DK_ + dd;
        short sh, sl; split1(v, sh, sl);
        ohi[off] = sh; olo[off] = sl;
      }
    }
  }
}

// ---------------------------------------------------------------------------
// Plain bf16 GEMM. MODE 0: A fp32 (V projection) -> bf16 head layout.
//                  MODE 1: A bf16 flat (out proj) -> fp32 flat.
// ---------------------------------------------------------------------------
template<int MODE>
__global__ __launch_bounds__(256) void kgemm(
    const float* __restrict__ af, const short* __restrict__ ab,
    const short* __restrict__ wtp, short* __restrict__ outb,
    float* __restrict__ outf)
{
  __shared__ short Alds[128][40];
  __shared__ short Wlds[128][40];

  const int m0 = blockIdx.x * 128;
  const int n0 = blockIdx.y * 128;

  const int tid  = threadIdx.x;
  const int w    = tid >> 6, lane = tid & 63;
  const int g    = lane >> 4, x = lane & 15;
  const int wr   = w >> 1, wc = w & 1;
  const int srow = tid >> 1, shalf = tid & 1;

  f32x4 acc[4][4];
#pragma unroll
  for (int mi = 0; mi < 4; mi++)
#pragma unroll
    for (int ni = 0; ni < 4; ni++) acc[mi][ni] = f32x4{0.f, 0.f, 0.f, 0.f};

  for (int k0 = 0; k0 < 1024; k0 += 32) {
    if constexpr (MODE == 0) {
      const float* ap = af + (size_t)(m0 + srow) * 1024 + k0 + shalf * 16;
      f32x4 fa = *(const f32x4*)(ap + 0);
      f32x4 fb = *(const f32x4*)(ap + 4);
      f32x4 fc = *(const f32x4*)(ap + 8);
      f32x4 fd = *(const f32x4*)(ap + 12);
      bf16x8 h0, h1;
#pragma unroll
      for (int j = 0; j < 4; j++) {
        h0[j] = f2bf(fa[j]); h0[4 + j] = f2bf(fb[j]);
        h1[j] = f2bf(fc[j]); h1[4 + j] = f2bf(fd[j]);
      }
      *(bf16x8*)&Alds[srow][shalf * 16 + 0] = h0;
      *(bf16x8*)&Alds[srow][shalf * 16 + 8] = h1;
    } else {
      const short* ap = ab + (size_t)(m0 + srow) * 1024 + k0 + shalf * 16;
      *(bf16x8*)&Alds[srow][shalf * 16 + 0] = *(const bf16x8*)(ap + 0);
      *(bf16x8*)&Alds[srow][shalf * 16 + 8] = *(const bf16x8*)(ap + 8);
    }
    {
      const short* wp = wtp + (size_t)(n0 + srow) * 1024 + k0 + shalf * 16;
      *(bf16x8*)&Wlds[srow][shalf * 16 + 0] = *(const bf16x8*)(wp + 0);
      *(bf16x8*)&Wlds[srow][shalf * 16 + 8] = *(const bf16x8*)(wp + 8);
    }
    __syncthreads();

    bf16x8 afr[4], bfr[4];
#pragma unroll
    for (int mi = 0; mi < 4; mi++)
      afr[mi] = *(const bf16x8*)&Alds[wr * 64 + mi * 16 + x][8 * g];
#pragma unroll
    for (int ni = 0; ni < 4; ni++)
      bfr[ni] = *(const bf16x8*)&Wlds[wc * 64 + ni * 16 + x][8 * g];
#pragma unroll
    for (int mi = 0; mi < 4; mi++)
#pragma unroll
      for (int ni = 0; ni < 4; ni++)
        acc[mi][ni] = __builtin_amdgcn_mfma_f32_16x16x32_bf16(
            afr[mi], bfr[ni], acc[mi][ni], 0, 0, 0);
    __syncthreads();
  }

#pragma unroll
  for (int mi = 0; mi < 4; mi++) {
    const int mrow = m0 + wr * 64 + mi * 16 + g * 4;
#pragma unroll
    for (int ni = 0; ni < 4; ni++) {
      const int ncol = n0 + wc * 64 + ni * 16 + x;
#pragma unroll
      for (int r = 0; r < 4; r++) {
        const float v = acc[mi][ni][r];
        const int row = mrow + r;
        if constexpr (MODE == 0) {
          const int b = row >> 11, s = row & 2047;
          const int hh = ncol >> 6, dd = ncol & 63;
          outb[(((size_t)b * H_ + hh) * S_ + s) * DK_ + dd] = f2bf(v);
        } else {
          outf[(size_t)row * 1024 + ncol] = v;
        }
      }
    }
  }
}

// ---------------------------------------------------------------------------
// Causal flash attention v2. Q,K bf16 hi/lo (3-MFMA split QK^T), V bf16.
// - Causal load-balance: block handles q-tile pair (p, 31-p): uniform 33
//   KV-iterations per block (was 3..67 -> 15% occupancy tail).
// - KVBLK=64: 32 MFMAs per barrier pair; LDS 36 KB -> 4 blocks/CU.
// - XCD-chunked swizzle: each XCD owns 8 bh's worth of blocks (K/V L2 reuse).
// - Scores arrive in log2-domain (scale folded into Q) -> native exp2f.
// Grid (16, 64), 256 thr = 4 waves x 16 q-rows.
// ---------------------------------------------------------------------------
__global__ __launch_bounds__(256) void kattn(
    const short* __restrict__ Qhi, const short* __restrict__ Qlo,
    const short* __restrict__ Khi, const short* __restrict__ Klo,
    const short* __restrict__ Vh,  short* __restrict__ AO)
{
  __shared__ short KldsH[64][72];   // stride 144B: 2-way max on b128 frags
  __shared__ short KldsL[64][72];
  __shared__ short Vtlds[64][72];   // V transposed [d][kv]
  __shared__ short Plds[4][16][72]; // per-wave P [q][kv]

  // XCD-chunked bijective swizzle: 1024 blocks, 8 XCDs, chunks of 128.
  const int flat = blockIdx.x + (blockIdx.y << 4);   // gridDim=(16,64)
  const int logical = (flat & 7) * 128 + (flat >> 3);
  const int p  = logical & 15;        // pair index 0..15
  const int bh = logical >> 4;        // 0..63

  const int tid = threadIdx.x;
  const int w = tid >> 6, lane = tid & 63;
  const int g = lane >> 4, x = lane & 15;

  const size_t bhoff = (size_t)bh * S_ * DK_;
  const short* KgH = Khi + bhoff;
  const short* KgL = Klo + bhoff;
  const short* Vg  = Vh + bhoff;

#pragma unroll
  for (int half = 0; half < 2; half++) {
    const int qt = half ? (31 - p) : p;          // q-tile index 0..31
    const int qb = qt * 64;

    const int qrow = qb + w * 16 + x;
    bf16x8 qfh[2], qfl[2];
#pragma unroll
    for (int ds = 0; ds < 2; ds++) {
      qfh[ds] = *(const bf16x8*)(Qhi + bhoff + (size_t)qrow * DK_ + ds * 32 + 8 * g);
      qfl[ds] = *(const bf16x8*)(Qlo + bhoff + (size_t)qrow * DK_ + ds * 32 + 8 * g);
    }

    f32x4 ow[4];
#pragma unroll
    for (int dt = 0; dt < 4; dt++) ow[dt] = f32x4{0.f, 0.f, 0.f, 0.f};
    float mrow[4], lsum[4];
#pragma unroll
    for (int r = 0; r < 4; r++) { mrow[r] = -1e30f; lsum[r] = 0.f; }

    const int ntiles = qt + 1;
    for (int it = 0; it < ntiles; it++) {
      const int kvb = it << 6;
      __syncthreads();   // previous iteration's LDS reads complete
      // ---- stage K hi/lo (b128) + V transposed (rotated scalar) ----
#pragma unroll
      for (int s = 0; s < 2; s++) {
        const int slot = tid + (s << 8);
        const int row = slot >> 3, c8 = slot & 7;
        const size_t goff = (size_t)(kvb + row) * DK_ + c8 * 8;
        *(bf16x8*)&KldsH[row][c8 * 8] = *(const bf16x8*)(KgH + goff);
        *(bf16x8*)&KldsL[row][c8 * 8] = *(const bf16x8*)(KgL + goff);
        bf16x8 vv = *(const bf16x8*)(Vg + goff);
        short va[8];
        *(bf16x8*)va = vv;
#pragma unroll
        for (int i = 0; i < 8; i++) {           // rotated write order
          const int e = (c8 + i) & 7;
          Vtlds[c8 * 8 + e][row] = va[e];
        }
      }
      __syncthreads();

      // ---- split QK^T : S[q 16][kv 64] per wave (24 MFMA) ----
      f32x4 sacc[4];
#pragma unroll
      for (int nt = 0; nt < 4; nt++) sacc[nt] = f32x4{0.f, 0.f, 0.f, 0.f};
      __builtin_amdgcn_s_setprio(1);
#pragma unroll
      for (int nt = 0; nt < 4; nt++)
#pragma unroll
        for (int ds = 0; ds < 2; ds++) {
          bf16x8 kfh = *(const bf16x8*)&KldsH[nt * 16 + x][ds * 32 + 8 * g];
          bf16x8 kfl = *(const bf16x8*)&KldsL[nt * 16 + x][ds * 32 + 8 * g];
          sacc[nt] = __builtin_amdgcn_mfma_f32_16x16x32_bf16(
              qfh[ds], kfh, sacc[nt], 0, 0, 0);
          sacc[nt] = __builtin_amdgcn_mfma_f32_16x16x32_bf16(
              qfh[ds], kfl, sacc[nt], 0, 0, 0);
          sacc[nt] = __builtin_amdgcn_mfma_f32_16x16x32_bf16(
              qfl[ds], kfh, sacc[nt], 0, 0, 0);
        }
      __builtin_amdgcn_s_setprio(0);

      // ---- causal mask (diagonal tile only: kvb == qb) ----
      if (kvb == qb) {
#pragma unroll
        for (int nt = 0; nt < 4; nt++) {
          const int kvg = kvb + nt * 16 + x;
#pragma unroll
          for (int r = 0; r < 4; r++) {
            const int qg = qb + w * 16 + g * 4 + r;
            if (kvg > qg) sacc[nt][r] = -1e30f;
          }
        }
      }

      // ---- online softmax (log2-domain scores, native exp2) ----
      float mnew[4], alpha[4];
#pragma unroll
      for (int r = 0; r < 4; r++) {
        float t = fmaxf(fmaxf(sacc[0][r], sacc[1][r]),
                        fmaxf(sacc[2][r], sacc[3][r]));
        t = fmaxf(t, __shfl_xor(t, 1));
        t = fmaxf(t, __shfl_xor(t, 2));
        t = fmaxf(t, __shfl_xor(t, 4));
        t = fmaxf(t, __shfl_xor(t, 8));
        mnew[r]  = fmaxf(mrow[r], t);
        alpha[r] = exp2f(mrow[r] - mnew[r]);
        mrow[r]  = mnew[r];
      }
#pragma unroll
      for (int r = 0; r < 4; r++) {
        float rs = 0.f;
#pragma unroll
        for (int nt = 0; nt < 4; nt++) {
          const float pe = exp2f(sacc[nt][r] - mnew[r]);
          sacc[nt][r] = pe;
          rs += pe;
        }
        rs += __shfl_xor(rs, 1);
        rs += __shfl_xor(rs, 2);
        rs += __shfl_xor(rs, 4);
        rs += __shfl_xor(rs, 8);
        lsum[r] = lsum[r] * alpha[r] + rs;
      }
#pragma unroll
      for (int nt = 0; nt < 4; nt++)
#pragma unroll
        for (int r = 0; r < 4; r++)
          Plds[w][g * 4 + r][nt * 16 + x] = f2bf(sacc[nt][r]);
#pragma unroll
      for (int dt = 0; dt < 4; dt++)
#pragma unroll
        for (int r = 0; r < 4; r++) ow[dt][r] *= alpha[r];

      // P writes are per-wave; fence LDS before reading them back
      asm volatile("s_waitcnt lgkmcnt(0)" ::: "memory");
      __builtin_amdgcn_sched_barrier(0);

      // ---- PV : O[q 16][d 64] (8 MFMA) ----
      bf16x8 pf[2];
      pf[0] = *(const bf16x8*)&Plds[w][x][0 * 32 + 8 * g];
      pf[1] = *(const bf16x8*)&Plds[w][x][1 * 32 + 8 * g];
      __builtin_amdgcn_s_setprio(1);
#pragma unroll
      for (int dt = 0; dt < 4; dt++)
#pragma unroll
        for (int ks = 0; ks < 2; ks++) {
          bf16x8 vf = *(const bf16x8*)&Vtlds[dt * 16 + x][ks * 32 + 8 * g];
          ow[dt] = __builtin_amdgcn_mfma_f32_16x16x32_bf16(
              pf[ks], vf, ow[dt], 0, 0, 0);
        }
      __builtin_amdgcn_s_setprio(0);
    }

    // ---- epilogue: normalize, write merged-head AO [B,S,D] bf16 ----
    const int b = bh >> 4, h = bh & 15;
#pragma unroll
    for (int r = 0; r < 4; r++) {
      const float inv = 1.0f / lsum[r];
      const int row = qb + w * 16 + g * 4 + r;
      const size_t base = ((size_t)b * S_ + row) * D_ + h * DK_;
#pragma unroll
      for (int dt = 0; dt < 4; dt++)
        AO[base + dt * 16 + x] = f2bf(ow[dt][r] * inv);
    }
  }
}

// ---------------------------------------------------------------------------
extern "C" void kernel_launch(void* const* d_in, const int* in_sizes, int n_in,
                              void* d_out, int out_size, void* d_ws, size_t ws_size,
                              hipStream_t stream) {
  (void)in_sizes; (void)n_in; (void)out_size; (void)ws_size;
  const float* q  = (const float*)d_in[0];
  const float* k  = (const float*)d_in[1];
  const float* v  = (const float*)d_in[2];
  const float* wq = (const float*)d_in[3];
  const float* wk = (const float*)d_in[4];
  const float* wv = (const float*)d_in[5];
  const float* wo = (const float*)d_in[6];
  float* out = (float*)d_out;

  // Workspace layout (MB):
  //   0..16   WT: 8 x [1024][1024] bf16 (wq_hi,wq_lo,wk_hi,wk_lo,wv_hi,wv_lo,wo_hi,wo_lo)
  //   16..32  QHhi   32..48 QHlo   48..64 KHhi   64..80 KHlo   (head-split bf16)
  //   80..96  VH (head-split bf16)
  //   96..112 AO ([B,S,D] bf16)
  char* ws = (char*)d_ws;
  short* WT   = (short*)ws;
  short* QKH  = (short*)(ws + (size_t)16 * 1024 * 1024);  // Q/K hi/lo base
  short* QHhi = QKH;
  short* QHlo = (short*)(ws + (size_t)32 * 1024 * 1024);
  short* KHhi = (short*)(ws + (size_t)48 * 1024 * 1024);
  short* KHlo = (short*)(ws + (size_t)64 * 1024 * 1024);
  short* VH   = (short*)(ws + (size_t)80 * 1024 * 1024);
  short* AO   = (short*)(ws + (size_t)96 * 1024 * 1024);

  const short* WVhi = WT + (size_t)4 * 1024 * 1024;
  const short* WOhi = WT + (size_t)6 * 1024 * 1024;

  kw_split<<<dim3(32, 32, 4), dim3(32, 8, 1), 0, stream>>>(wq, wk, wv, wo, WT);
  kproj_qk<<<dim3(64, 8, 2), dim3(256), 0, stream>>>(q, k, WT, QKH);
  kgemm<0><<<dim3(64, 8), dim3(256), 0, stream>>>(v, nullptr, WVhi, VH, nullptr);
  kattn<<<dim3(16, 64), dim3(256), 0, stream>>>(QHhi, QHlo, KHhi, KHlo, VH, AO);
  kgemm<1><<<dim3(64, 8), dim3(256), 0, stream>>>(nullptr, AO, WOhi, nullptr, out);
}